// Round 2
// baseline (612.282 us; speedup 1.0000x reference)
//
#include <hip/hip_runtime.h>

// Local cost-volume correlation, fp32 vector path, DPP window sharing.
// out[b, dy*9+dx, h, w] = (1/256) sum_c in1[b,c,h,w] * in2[b,c,h+dy-4,w+dx-4]
//
// R5 design (from R4 post-mortem: latency-bound — VALUBusy 36%, HBM 11%,
// occupancy 34% (grid-limited 3.4 waves/SIMD), only ~4 loads in flight):
//  - keep R4's wave layout + DPP window core (proven correct)
//  - channel loop restructured as explicit ping-pong double buffer of
//    4-channel groups: 8 float4 loads per group issued while the OTHER
//    group computes (~400 VALU cyc of FMA+DPP) -> up to 16 loads in
//    flight, per-wave latency self-hiding instead of relying on TLP
//  - staging regs 2*4*2 float4 = 64 VGPR + 36 acc ~= 115 total, stays
//    under the 128-VGPR / 4-waves-per-SIMD cliff (launch_bounds kept)
// (R5 resubmission — previous round hit GPUAcquisitionTimeout, never ran.)

#define CH 256
#define HH 96
#define WW 128
#define CS (HH * WW)
#define CS4 (CS / 4)   // float4s per channel plane = 3072

__device__ __forceinline__ float wshr1(float x) {  // lane i <- lane i-1
  union { float f; int i; } u, o;
  u.f = x;
  o.i = __builtin_amdgcn_update_dpp(0, u.i, 0x138, 0xF, 0xF, true);
  return o.f;
}
__device__ __forceinline__ float wshl1(float x) {  // lane i <- lane i+1
  union { float f; int i; } u, o;
  u.f = x;
  o.i = __builtin_amdgcn_update_dpp(0, u.i, 0x130, 0xF, 0xF, true);
  return o.f;
}

// load one 4-channel group (8 float4s) into buffers, advance pointers
#define LOADG(Ab, Mb)                                   \
  do {                                                  \
    _Pragma("unroll")                                   \
    for (int u = 0; u < 4; ++u) {                       \
      Ab[u] = q1[u * CS4];                              \
      Mb[u] = q2[u * CS4];                              \
    }                                                   \
    q1 += 4 * CS4;                                      \
    q2 += 4 * CS4;                                      \
  } while (0)

// consume one 4-channel group: DPP window + 36 FMAs per channel
#define COMPG(Ab, Mb)                                                   \
  do {                                                                  \
    _Pragma("unroll")                                                   \
    for (int u = 0; u < 4; ++u) {                                       \
      const float4 a4 = Ab[u];                                          \
      const float4 m4 = Mb[u];                                          \
      float w[12];                                                      \
      w[0] = wshr1(m4.x); w[1] = wshr1(m4.y);                           \
      w[2] = wshr1(m4.z); w[3] = wshr1(m4.w);                           \
      w[4] = m4.x; w[5] = m4.y; w[6] = m4.z; w[7] = m4.w;               \
      w[8] = wshl1(m4.x); w[9] = wshl1(m4.y);                           \
      w[10] = wshl1(m4.z); w[11] = wshl1(m4.w);                         \
      const float av[4] = {a4.x, a4.y, a4.z, a4.w};                     \
      _Pragma("unroll")                                                 \
      for (int p = 0; p < 4; ++p)                                       \
        _Pragma("unroll")                                               \
        for (int d = 0; d < 9; ++d)                                     \
          acc[p][d] = fmaf(av[p], w[p + d], acc[p][d]);                 \
    }                                                                   \
  } while (0)

__global__ __launch_bounds__(256, 4) void corr_dpp(
    const float* __restrict__ in1, const float* __restrict__ in2,
    float* __restrict__ out)
{
  // ---- block decode, XCD-swizzled: tile's 9 dy-blocks share blockIdx%8 ----
  const int j    = blockIdx.x;          // grid = 864
  const int xcd  = j & 7;
  const int s    = j >> 3;              // 0..107
  const int dy   = s % 9;
  const int tq   = s / 9;               // 0..11
  const int tile = tq * 8 + xcd;        // 0..95
  const int band = tile % 12;
  const int b    = tile / 12;
  const int dyo  = dy - 4;

  // ---- thread decode: 4 waves x (2 rows x 32 col-groups), 4 px/lane ----
  const int tid  = threadIdx.x;
  const int wv   = tid >> 6;
  const int lane = tid & 63;
  const int r    = lane >> 5;
  const int g    = lane & 31;
  const int h    = band * 8 + wv * 2 + r;   // 0..95, always valid
  const int px   = g << 2;                  // 0..124
  const int r2   = h + dyo;                 // in2 row, may be OOB
  const bool rowok = (unsigned)r2 < (unsigned)HH;
  const int r2c  = r2 < 0 ? 0 : (r2 > HH - 1 ? HH - 1 : r2);

  const float4* q1 = (const float4*)(in1 + ((size_t)b * CH * HH + h)   * WW + px);
  const float4* q2 = (const float4*)(in2 + ((size_t)b * CH * HH + r2c) * WW + px);

  float acc[4][9];
#pragma unroll
  for (int p = 0; p < 4; ++p)
#pragma unroll
    for (int d = 0; d < 9; ++d) acc[p][d] = 0.f;

  float4 A0[4], M0[4], A1[4], M1[4];

  // ---- ping-pong double-buffered channel loop: 64 groups of 4 channels ----
  LOADG(A0, M0);                       // group 0
#pragma unroll 1
  for (int cc = 0; cc < CH - 8; cc += 8) {
    LOADG(A1, M1);                     // group cc/4 + 1
    COMPG(A0, M0);                     // group cc/4
    LOADG(A0, M0);                     // group cc/4 + 2
    COMPG(A1, M1);                     // group cc/4 + 1
  }
  LOADG(A1, M1);                       // last group (c = 252..255)
  COMPG(A0, M0);
  COMPG(A1, M1);

  // ---- epilogue: zero OOB (row + col) contributions, scale, float4 store ----
  const float sc = 1.0f / (float)CH;
  float* po = out + (((size_t)b * 81 + dy * 9) * HH + h) * WW + px;
#pragma unroll
  for (int d = 0; d < 9; ++d) {
    float v[4];
#pragma unroll
    for (int p = 0; p < 4; ++p) {
      const int col2 = px + p + d - 4;                       // in2 column
      const bool ok  = rowok && ((unsigned)col2 < (unsigned)WW);
      v[p] = ok ? acc[p][d] * sc : 0.f;
    }
    *(float4*)po = make_float4(v[0], v[1], v[2], v[3]);
    po += (size_t)CS;  // next (dy,dx) plane
  }
}

extern "C" void kernel_launch(void* const* d_in, const int* in_sizes, int n_in,
                              void* d_out, int out_size, void* d_ws, size_t ws_size,
                              hipStream_t stream) {
  const float* in1 = (const float*)d_in[0];
  const float* in2 = (const float*)d_in[1];
  float* out = (float*)d_out;
  hipLaunchKernelGGL(corr_dpp, dim3(864), dim3(256), 0, stream, in1, in2, out);
}